// Round 3
// baseline (187.975 us; speedup 1.0000x reference)
//
#include <hip/hip_runtime.h>
#include <hip/hip_bf16.h>
#include <math.h>

#define BB 4
#define NN 512
#define DD 256
#define LL 64

#define K1_NR 4   // x rows per block in projection kernel
#define IPB  8    // i-rows per block in main kernel

// ---------------------------------------------------------------------------
// k1: x_hatT[b][l][n] = sum_d x[b][n][d] * W[l][d]
// Transposed output so k2's per-j reads are lane-coalesced.
// W staged in LDS (two 128-col halves, row stride 129 -> bank = (l+d)%32, free).
// ---------------------------------------------------------------------------
__global__ __launch_bounds__(256) void k1_proj(const float* __restrict__ x,
                                               const float* __restrict__ Wp,
                                               float* __restrict__ xhatT) {
  __shared__ float Wl[LL * 129];      // 33,024 B
  __shared__ float xs[K1_NR * DD];    //  4,096 B
  const int bx = blockIdx.x;
  const int b  = bx / (NN / K1_NR);
  const int n0 = (bx % (NN / K1_NR)) * K1_NR;
  const int t  = threadIdx.x;
  const int l  = t & 63;
  const int r  = t >> 6;

  // stage K1_NR rows of x, coalesced
  #pragma unroll
  for (int k = 0; k < K1_NR; ++k)
    xs[k * DD + t] = x[((size_t)(b * NN + n0 + k)) * DD + t];

  float acc = 0.f;
  #pragma unroll
  for (int h = 0; h < 2; ++h) {
    __syncthreads();                  // protects xs (h=0) / Wl reuse (h=1)
    // stage W half h: 64 rows x 128 cols, coalesced in 128-float runs
    #pragma unroll
    for (int kk = 0; kk < 32; ++kk) {
      int idx = kk * 256 + t;
      int ll  = idx >> 7;
      int dd  = idx & 127;
      Wl[ll * 129 + dd] = Wp[ll * DD + h * 128 + dd];
    }
    __syncthreads();
    const float* xrow = &xs[r * DD + h * 128];   // wave-uniform -> broadcast
    const float* wrow = &Wl[l * 129];            // bank (l+dd)%32 -> conflict-free
    #pragma unroll 16
    for (int dd = 0; dd < 128; ++dd)
      acc += xrow[dd] * wrow[dd];
  }
  xhatT[(size_t)b * (LL * NN) + (size_t)l * NN + (n0 + r)] = acc;
}

// ---------------------------------------------------------------------------
// k2: per (b, i-tile of 8): dist -> leaky_relu -> rowmax -> adj*exp -> rowsum
//     -> divide -> +1e-10.  512 threads, thread = column j.
// xi pre-scaled by w (w>=0 so w*|xi-xj| == |w*xi - w*xj|), stored [l][r]
// so the 8 per-l values come from two broadcast ds_read_b128.
// ---------------------------------------------------------------------------
__global__ __launch_bounds__(512) void k2_main(const float* __restrict__ xhatT,
                                               const float* __restrict__ adj,
                                               const float* __restrict__ lw,
                                               float* __restrict__ out) {
  __shared__ __align__(16) float xi_s[LL * IPB];  // [l][r], pre-scaled by w
  __shared__ float w_s[LL];
  __shared__ float redm[IPB * 8];
  __shared__ float reds[IPB * 8];

  const int bx   = blockIdx.x;
  const int b    = bx / (NN / IPB);
  const int i0   = (bx % (NN / IPB)) * IPB;
  const int t    = threadIdx.x;      // j
  const int wave = t >> 6;
  const int lane = t & 63;

  const float* xb = xhatT + (size_t)b * (LL * NN);

  {
    int l = t >> 3, r = t & 7;       // 512 threads cover LL*IPB exactly
    xi_s[t] = lw[l] * xb[l * NN + i0 + r];
  }
  if (t < LL) w_s[t] = lw[t];
  __syncthreads();

  float acc[IPB];
  #pragma unroll
  for (int r = 0; r < IPB; ++r) acc[r] = 0.f;

  const float4* xi4 = (const float4*)xi_s;
  #pragma unroll
  for (int l = 0; l < LL; ++l) {
    float pj = w_s[l] * xb[l * NN + t];   // coalesced, L2-resident
    float4 a = xi4[l * 2 + 0];            // broadcast b128
    float4 c = xi4[l * 2 + 1];
    acc[0] += fabsf(a.x - pj);
    acc[1] += fabsf(a.y - pj);
    acc[2] += fabsf(a.z - pj);
    acc[3] += fabsf(a.w - pj);
    acc[4] += fabsf(c.x - pj);
    acc[5] += fabsf(c.y - pj);
    acc[6] += fabsf(c.z - pj);
    acc[7] += fabsf(c.w - pj);
  }

  // leaky_relu (dist >= 0 in practice, but stay faithful)
  #pragma unroll
  for (int r = 0; r < IPB; ++r) {
    float d = acc[r];
    acc[r] = d >= 0.f ? d : 0.01f * d;
  }

  // row max over 512 j: wave shfl reduce, then cross-wave via LDS
  #pragma unroll
  for (int r = 0; r < IPB; ++r) {
    float m = acc[r];
    #pragma unroll
    for (int off = 32; off > 0; off >>= 1)
      m = fmaxf(m, __shfl_xor(m, off, 64));
    if (lane == 0) redm[r * 8 + wave] = m;
  }
  __syncthreads();

  float e[IPB];
  const float* adjb = adj + ((size_t)b * NN + i0) * NN;
  #pragma unroll
  for (int r = 0; r < IPB; ++r) {
    float m = redm[r * 8 + 0];
    #pragma unroll
    for (int k = 1; k < 8; ++k) m = fmaxf(m, redm[r * 8 + k]);  // broadcast reads
    e[r] = adjb[(size_t)r * NN + t] * __expf(acc[r] - m);
  }

  // row sum
  #pragma unroll
  for (int r = 0; r < IPB; ++r) {
    float s = e[r];
    #pragma unroll
    for (int off = 32; off > 0; off >>= 1)
      s += __shfl_xor(s, off, 64);
    if (lane == 0) reds[r * 8 + wave] = s;
  }
  __syncthreads();

  float* outb = out + ((size_t)b * NN + i0) * NN;
  #pragma unroll
  for (int r = 0; r < IPB; ++r) {
    float s = reds[r * 8 + 0];
    #pragma unroll
    for (int k = 1; k < 8; ++k) s += reds[r * 8 + k];
    outb[(size_t)r * NN + t] = e[r] / s + 1e-10f;   // epsilon AFTER division
  }
}

extern "C" void kernel_launch(void* const* d_in, const int* in_sizes, int n_in,
                              void* d_out, int out_size, void* d_ws, size_t ws_size,
                              hipStream_t stream) {
  const float* x   = (const float*)d_in[0];   // [B,N,D]
  const float* adj = (const float*)d_in[1];   // [B,N,N]
  const float* Wp  = (const float*)d_in[2];   // [L,D]
  const float* lw  = (const float*)d_in[3];   // [L]
  float* out   = (float*)d_out;               // [B,N,N]
  float* xhatT = (float*)d_ws;                // B*L*N floats = 512 KiB

  hipLaunchKernelGGL(k1_proj, dim3(BB * NN / K1_NR), dim3(256), 0, stream,
                     x, Wp, xhatT);
  hipLaunchKernelGGL(k2_main, dim3(BB * NN / IPB), dim3(512), 0, stream,
                     xhatT, adj, lw, out);
}

// Round 4
// 81.052 us; speedup vs baseline: 2.3192x; 2.3192x over previous
//
#include <hip/hip_runtime.h>
#include <hip/hip_bf16.h>
#include <math.h>

#define BB 4
#define NN 512
#define DD 256
#define LL 64

#define K1_NR 4   // x rows per block in projection kernel
#define IPB  8    // i-rows per block in main kernel

// ---------------------------------------------------------------------------
// k1: x_hatT[b][l][n] = sum_d x[b][n][d] * W[l][d]
// Transposed output so k2's per-j reads are lane-coalesced.
// W staged in LDS (two 128-col halves, row stride 129 -> bank = (l+d)%32, free).
// (unchanged this round for clean attribution of the k2 spill fix)
// ---------------------------------------------------------------------------
__global__ __launch_bounds__(256) void k1_proj(const float* __restrict__ x,
                                               const float* __restrict__ Wp,
                                               float* __restrict__ xhatT) {
  __shared__ float Wl[LL * 129];      // 33,024 B
  __shared__ float xs[K1_NR * DD];    //  4,096 B
  const int bx = blockIdx.x;
  const int b  = bx / (NN / K1_NR);
  const int n0 = (bx % (NN / K1_NR)) * K1_NR;
  const int t  = threadIdx.x;
  const int l  = t & 63;
  const int r  = t >> 6;

  // stage K1_NR rows of x, coalesced
  #pragma unroll
  for (int k = 0; k < K1_NR; ++k)
    xs[k * DD + t] = x[((size_t)(b * NN + n0 + k)) * DD + t];

  float acc = 0.f;
  #pragma unroll
  for (int h = 0; h < 2; ++h) {
    __syncthreads();                  // protects xs (h=0) / Wl reuse (h=1)
    // stage W half h: 64 rows x 128 cols, coalesced in 128-float runs
    #pragma unroll
    for (int kk = 0; kk < 32; ++kk) {
      int idx = kk * 256 + t;
      int ll  = idx >> 7;
      int dd  = idx & 127;
      Wl[ll * 129 + dd] = Wp[ll * DD + h * 128 + dd];
    }
    __syncthreads();
    const float* xrow = &xs[r * DD + h * 128];   // wave-uniform -> broadcast
    const float* wrow = &Wl[l * 129];            // bank (l+dd)%32 -> conflict-free
    #pragma unroll 16
    for (int dd = 0; dd < 128; ++dd)
      acc += xrow[dd] * wrow[dd];
  }
  xhatT[(size_t)b * (LL * NN) + (size_t)l * NN + (n0 + r)] = acc;
}

// ---------------------------------------------------------------------------
// k2: per (b, i-tile of 8): dist -> leaky_relu -> rowmax -> adj*exp -> rowsum
//     -> divide -> +1e-10.  512 threads, thread = column j.
// SPILL FIX: l-loop partial unroll (4). Full unroll let the scheduler hoist
// 64 global loads + 128 LDS float4 reads -> ~1.4 KB/thread scratch spill
// (WRITE_SIZE 182 MB vs 4 MB legit). unroll 4 bounds live ranges.
// ---------------------------------------------------------------------------
__global__ __launch_bounds__(512) void k2_main(const float* __restrict__ xhatT,
                                               const float* __restrict__ adj,
                                               const float* __restrict__ lw,
                                               float* __restrict__ out) {
  __shared__ __align__(16) float xi_s[LL * IPB];  // [l][r], pre-scaled by w
  __shared__ float w_s[LL];
  __shared__ float redm[IPB * 8];
  __shared__ float reds[IPB * 8];

  const int bx   = blockIdx.x;
  const int b    = bx / (NN / IPB);
  const int i0   = (bx % (NN / IPB)) * IPB;
  const int t    = threadIdx.x;      // j
  const int wave = t >> 6;
  const int lane = t & 63;

  const float* xb = xhatT + (size_t)b * (LL * NN);

  {
    int l = t >> 3, r = t & 7;       // 512 threads cover LL*IPB exactly
    xi_s[t] = lw[l] * xb[l * NN + i0 + r];
  }
  if (t < LL) w_s[t] = lw[t];
  __syncthreads();

  float acc[IPB];
  #pragma unroll
  for (int r = 0; r < IPB; ++r) acc[r] = 0.f;

  const float4* xi4 = (const float4*)xi_s;
  #pragma unroll 4
  for (int l = 0; l < LL; ++l) {
    float pj = w_s[l] * xb[l * NN + t];   // coalesced, L2-resident
    float4 a = xi4[l * 2 + 0];            // broadcast b128
    float4 c = xi4[l * 2 + 1];
    acc[0] += fabsf(a.x - pj);
    acc[1] += fabsf(a.y - pj);
    acc[2] += fabsf(a.z - pj);
    acc[3] += fabsf(a.w - pj);
    acc[4] += fabsf(c.x - pj);
    acc[5] += fabsf(c.y - pj);
    acc[6] += fabsf(c.z - pj);
    acc[7] += fabsf(c.w - pj);
  }

  // leaky_relu (dist >= 0 in practice, but stay faithful)
  #pragma unroll
  for (int r = 0; r < IPB; ++r) {
    float d = acc[r];
    acc[r] = d >= 0.f ? d : 0.01f * d;
  }

  // row max over 512 j: wave shfl reduce, then cross-wave via LDS
  #pragma unroll
  for (int r = 0; r < IPB; ++r) {
    float m = acc[r];
    #pragma unroll
    for (int off = 32; off > 0; off >>= 1)
      m = fmaxf(m, __shfl_xor(m, off, 64));
    if (lane == 0) redm[r * 8 + wave] = m;
  }
  __syncthreads();

  float e[IPB];
  const float* adjb = adj + ((size_t)b * NN + i0) * NN;
  #pragma unroll
  for (int r = 0; r < IPB; ++r) {
    float m = redm[r * 8 + 0];
    #pragma unroll
    for (int k = 1; k < 8; ++k) m = fmaxf(m, redm[r * 8 + k]);  // broadcast reads
    e[r] = adjb[(size_t)r * NN + t] * __expf(acc[r] - m);
  }

  // row sum
  #pragma unroll
  for (int r = 0; r < IPB; ++r) {
    float s = e[r];
    #pragma unroll
    for (int off = 32; off > 0; off >>= 1)
      s += __shfl_xor(s, off, 64);
    if (lane == 0) reds[r * 8 + wave] = s;
  }
  __syncthreads();

  float* outb = out + ((size_t)b * NN + i0) * NN;
  #pragma unroll
  for (int r = 0; r < IPB; ++r) {
    float s = reds[r * 8 + 0];
    #pragma unroll
    for (int k = 1; k < 8; ++k) s += reds[r * 8 + k];
    outb[(size_t)r * NN + t] = e[r] / s + 1e-10f;   // epsilon AFTER division
  }
}

extern "C" void kernel_launch(void* const* d_in, const int* in_sizes, int n_in,
                              void* d_out, int out_size, void* d_ws, size_t ws_size,
                              hipStream_t stream) {
  const float* x   = (const float*)d_in[0];   // [B,N,D]
  const float* adj = (const float*)d_in[1];   // [B,N,N]
  const float* Wp  = (const float*)d_in[2];   // [L,D]
  const float* lw  = (const float*)d_in[3];   // [L]
  float* out   = (float*)d_out;               // [B,N,N]
  float* xhatT = (float*)d_ws;                // B*L*N floats = 512 KiB

  hipLaunchKernelGGL(k1_proj, dim3(BB * NN / K1_NR), dim3(256), 0, stream,
                     x, Wp, xhatT);
  hipLaunchKernelGGL(k2_main, dim3(BB * NN / IPB), dim3(512), 0, stream,
                     xhatT, adj, lw, out);
}

// Round 5
// 77.580 us; speedup vs baseline: 2.4230x; 1.0448x over previous
//
#include <hip/hip_runtime.h>
#include <hip/hip_bf16.h>
#include <math.h>

#define BB 4
#define NN 512
#define DD 256
#define LL 64

#define K1_NR 4   // x rows per block in projection kernel
#define IPB  4    // i-rows per block in main kernel (4 -> 512 blocks = 2/CU)
#define WSTRIDE 132  // 128 cols + 4 pad: b128 bank pattern == conflict-free optimum

// ---------------------------------------------------------------------------
// k1: x_hatT[b][l][n] = sum_d x[b][n][d] * W[l][d]
// Transposed output so k2's per-j reads are lane-coalesced.
// This round: float4 LDS reads (4x fewer LDS-pipe instrs) + 4 accumulators
// (breaks the serial FMA chain). W staged in two 128-col halves, row stride
// 132 floats -> float4 at dd%4==0 is 16B-aligned; 8 lanes/4-bank group with
// 8 distinct words each == the same 8-phase service as contiguous b128.
// ---------------------------------------------------------------------------
__global__ __launch_bounds__(256) void k1_proj(const float* __restrict__ x,
                                               const float* __restrict__ Wp,
                                               float* __restrict__ xhatT) {
  __shared__ __align__(16) float Wl[LL * WSTRIDE]; // 33,792 B
  __shared__ __align__(16) float xs[K1_NR * DD];   //  4,096 B
  const int bx = blockIdx.x;
  const int b  = bx / (NN / K1_NR);
  const int n0 = (bx % (NN / K1_NR)) * K1_NR;
  const int t  = threadIdx.x;
  const int l  = t & 63;
  const int r  = t >> 6;

  // stage K1_NR rows of x, coalesced
  #pragma unroll
  for (int k = 0; k < K1_NR; ++k)
    xs[k * DD + t] = x[((size_t)(b * NN + n0 + k)) * DD + t];

  float4 acc4 = make_float4(0.f, 0.f, 0.f, 0.f);
  #pragma unroll
  for (int h = 0; h < 2; ++h) {
    __syncthreads();                  // protects xs (h=0) / Wl reuse (h=1)
    // stage W half h: 64 rows x 128 cols, coalesced in 128-float runs
    #pragma unroll
    for (int kk = 0; kk < 32; ++kk) {
      int idx = kk * 256 + t;
      int ll  = idx >> 7;
      int dd  = idx & 127;
      Wl[ll * WSTRIDE + dd] = Wp[ll * DD + h * 128 + dd];
    }
    __syncthreads();
    const float4* xrow = (const float4*)&xs[r * DD + h * 128]; // wave-uniform
    const float4* wrow = (const float4*)&Wl[l * WSTRIDE];
    #pragma unroll 4
    for (int dd = 0; dd < 32; ++dd) {
      float4 xv = xrow[dd];
      float4 wv = wrow[dd];
      acc4.x += xv.x * wv.x;
      acc4.y += xv.y * wv.y;
      acc4.z += xv.z * wv.z;
      acc4.w += xv.w * wv.w;
    }
  }
  float acc = (acc4.x + acc4.y) + (acc4.z + acc4.w);
  xhatT[(size_t)b * (LL * NN) + (size_t)l * NN + (n0 + r)] = acc;
}

// ---------------------------------------------------------------------------
// k2: per (b, i-tile of IPB): dist -> leaky_relu -> rowmax -> adj*exp ->
//     rowsum -> divide -> +1e-10.  512 threads, thread = column j.
// IPB=4 -> 512 blocks = 2 blocks/CU (was 1) for latency hiding; the xi tile
// per l is exactly one broadcast ds_read_b128. Partial unroll keeps live
// ranges bounded (round-3 lesson: full unroll spilled 1.4 KB/thread).
// ---------------------------------------------------------------------------
__global__ __launch_bounds__(512) void k2_main(const float* __restrict__ xhatT,
                                               const float* __restrict__ adj,
                                               const float* __restrict__ lw,
                                               float* __restrict__ out) {
  __shared__ __align__(16) float xi_s[LL * IPB];  // [l][r], pre-scaled by w
  __shared__ float w_s[LL];
  __shared__ float redm[IPB * 8];
  __shared__ float reds[IPB * 8];

  const int bx   = blockIdx.x;
  const int b    = bx / (NN / IPB);
  const int i0   = (bx % (NN / IPB)) * IPB;
  const int t    = threadIdx.x;      // j
  const int wave = t >> 6;
  const int lane = t & 63;

  const float* xb = xhatT + (size_t)b * (LL * NN);

  if (t < LL * IPB) {                // 256 threads stage the xi tile
    int l = t >> 2, r = t & 3;
    xi_s[t] = lw[l] * xb[l * NN + i0 + r];
  }
  if (t < LL) w_s[t] = lw[t];
  __syncthreads();

  float acc[IPB];
  #pragma unroll
  for (int r = 0; r < IPB; ++r) acc[r] = 0.f;

  const float4* xi4 = (const float4*)xi_s;
  #pragma unroll 4
  for (int l = 0; l < LL; ++l) {
    float pj = w_s[l] * xb[l * NN + t];   // coalesced, L2-resident
    float4 a = xi4[l];                    // broadcast b128
    acc[0] += fabsf(a.x - pj);
    acc[1] += fabsf(a.y - pj);
    acc[2] += fabsf(a.z - pj);
    acc[3] += fabsf(a.w - pj);
  }

  // leaky_relu (dist >= 0 in practice, but stay faithful)
  #pragma unroll
  for (int r = 0; r < IPB; ++r) {
    float d = acc[r];
    acc[r] = d >= 0.f ? d : 0.01f * d;
  }

  // row max over 512 j: wave shfl reduce, then cross-wave via LDS
  #pragma unroll
  for (int r = 0; r < IPB; ++r) {
    float m = acc[r];
    #pragma unroll
    for (int off = 32; off > 0; off >>= 1)
      m = fmaxf(m, __shfl_xor(m, off, 64));
    if (lane == 0) redm[r * 8 + wave] = m;
  }
  __syncthreads();

  float e[IPB];
  const float* adjb = adj + ((size_t)b * NN + i0) * NN;
  #pragma unroll
  for (int r = 0; r < IPB; ++r) {
    float m = redm[r * 8 + 0];
    #pragma unroll
    for (int k = 1; k < 8; ++k) m = fmaxf(m, redm[r * 8 + k]);  // broadcast reads
    e[r] = adjb[(size_t)r * NN + t] * __expf(acc[r] - m);
  }

  // row sum
  #pragma unroll
  for (int r = 0; r < IPB; ++r) {
    float s = e[r];
    #pragma unroll
    for (int off = 32; off > 0; off >>= 1)
      s += __shfl_xor(s, off, 64);
    if (lane == 0) reds[r * 8 + wave] = s;
  }
  __syncthreads();

  float* outb = out + ((size_t)b * NN + i0) * NN;
  #pragma unroll
  for (int r = 0; r < IPB; ++r) {
    float s = reds[r * 8 + 0];
    #pragma unroll
    for (int k = 1; k < 8; ++k) s += reds[r * 8 + k];
    outb[(size_t)r * NN + t] = e[r] / s + 1e-10f;   // epsilon AFTER division
  }
}

extern "C" void kernel_launch(void* const* d_in, const int* in_sizes, int n_in,
                              void* d_out, int out_size, void* d_ws, size_t ws_size,
                              hipStream_t stream) {
  const float* x   = (const float*)d_in[0];   // [B,N,D]
  const float* adj = (const float*)d_in[1];   // [B,N,N]
  const float* Wp  = (const float*)d_in[2];   // [L,D]
  const float* lw  = (const float*)d_in[3];   // [L]
  float* out   = (float*)d_out;               // [B,N,N]
  float* xhatT = (float*)d_ws;                // B*L*N floats = 512 KiB

  hipLaunchKernelGGL(k1_proj, dim3(BB * NN / K1_NR), dim3(256), 0, stream,
                     x, Wp, xhatT);
  hipLaunchKernelGGL(k2_main, dim3(BB * NN / IPB), dim3(512), 0, stream,
                     xhatT, adj, lw, out);
}